// Round 8
// baseline (153.957 us; speedup 1.0000x reference)
//
#include <hip/hip_runtime.h>
#include <hip/hip_bf16.h>

// CrossAttention fused pipeline, MI355X (gfx950)
// B=2, N=160, D=4096, H=4, DH=1024, SCALE=1/32 (applied twice)
//
// R8: DRAM-friendly W streaming. Per block, W is fetched in 1 KB-contiguous
// wave-wide f32x4 instructions (copy-kernel pattern -> near-peak DRAM
// efficiency), staged via 2x16 KB LDS chunks ([32 rows][256 f32]), chunk c+1
// reg-prefetched during compute of c. A is read direct-to-register from the
// XCD-pinned L2-resident chunk. 4 blocks/CU. All stores plain (L2 coalesces;
// nt scattered stores were the R7 "rest" regression).
//
// Stage 0: cvt x,y f32 -> bf16
// Stage 1+2: qk GEMM: BM=320, BN=32, Ksplit=4 (Kc=1024). 1024 blocks.
//   key=blockIdx&7=(z<<2)|ks -> XCD pin. bf16 partials P[8][320][4096].
// Stage 2b: reduce 4 partials -> qT[b][d][n] (transposed) and k[320][4096]
// Stage 3: kkt = SCALE * k.k^T per (b,h)      (bf16)
// Stage 4: out = softplus(SCALE * qT @ kkt^T) (f32)

typedef __attribute__((ext_vector_type(4))) float  f32x4;
typedef __attribute__((ext_vector_type(8))) __bf16 bf16x8;
typedef __attribute__((ext_vector_type(4))) __bf16 bf16x4;

#define SCALE 0.03125f

static __device__ __forceinline__ f32x4 mfma16(bf16x8 a, bf16x8 b, f32x4 c) {
    return __builtin_amdgcn_mfma_f32_16x16x32_bf16(a, b, c, 0, 0, 0);
}

static __device__ __forceinline__ bf16x8 pack8(f32x4 a, f32x4 b) {
    bf16x8 r;
    #pragma unroll
    for (int i = 0; i < 4; ++i) { r[i] = (__bf16)a[i]; r[4 + i] = (__bf16)b[i]; }
    return r;
}

static __device__ __forceinline__ bf16x8 pack8f(const float* v) {
    bf16x8 r;
    #pragma unroll
    for (int i = 0; i < 8; ++i) r[i] = (__bf16)v[i];
    return r;
}

static __device__ __forceinline__ float softplus(float x) {
    return fmaxf(x, 0.0f) + log1pf(expf(-fabsf(x)));
}

// ---------------------------------------------------------------------------
// Stage 0: f32 -> bf16 conversion of activations. grid (640, 2), 256 thr.
// ---------------------------------------------------------------------------
__global__ __launch_bounds__(256)
void cvt_kernel(const float* __restrict__ x, const float* __restrict__ y,
                __bf16* __restrict__ xb, __bf16* __restrict__ yb)
{
    const float* src = blockIdx.y ? y : x;
    __bf16* dst = blockIdx.y ? yb : xb;
    size_t i = ((size_t)blockIdx.x * 256 + threadIdx.x) * 8;
    f32x4 a = *(const f32x4*)(src + i);
    f32x4 b = *(const f32x4*)(src + i + 4);
    *(bf16x8*)(dst + i) = pack8(a, b);
}

// ---------------------------------------------------------------------------
// Stage 1+2: C(320x4096) = A(320x4096,bf16) @ W^T, K-split 4, bf16 partials.
// grid 1024 flat: key = blockIdx&7 = (z<<2)|ks [XCD pin], np = blockIdx>>3
// (BN=32 panel). 256 thr = 4 waves, wave tile 80x32 (acc[5][2]).
// Kc=1024 = 4 chunks of 256 f32; chunk fetch = 8 wave-wide f32x4 reads
// (1 KB contiguous per row); double-buffered 16 KB LDS; chunk c+1 is
// reg-prefetched during compute of chunk c (4 inner BK=64 steps).
// A-frags loaded per wave direct from L2 (XCD-resident 640 KB chunk).
// ---------------------------------------------------------------------------
__global__ __launch_bounds__(256, 4)
void qk_gemm(const __bf16* __restrict__ yb, const __bf16* __restrict__ xb,
             const float* __restrict__ Wq, const float* __restrict__ Wk,
             __bf16* __restrict__ P)
{
    const int key = blockIdx.x & 7;
    const int z   = key >> 2;             // 0: q (A=yb,W=Wq)  1: k (A=xb,W=Wk)
    const int ks  = key & 3;
    const int np  = blockIdx.x >> 3;      // 0..127
    const int bn  = np * 32;
    const int kc  = ks * 1024;

    __shared__ __bf16 lW[2][32 * 256];    // 16 KB per buffer

    const int tid  = threadIdx.x;
    const int lane = tid & 63;
    const int wid  = tid >> 6;
    const int li   = lane & 15;
    const int lk   = lane >> 4;

    const __bf16* __restrict__ Ab = z ? xb : yb;   // [320][4096]
    const float*  __restrict__ Wm = z ? Wk : Wq;

    // W fetch: wave wid owns rows wid*8..+7; lane reads f32x4 at col lane*4
    // -> one instruction = 1 KB contiguous of one W row.
    const float* wbase = Wm + (size_t)(bn + wid * 8) * 4096 + kc + lane * 4;

    // A fragment row pointers (per-wave private rows).
    const __bf16* ap[5];
    #pragma unroll
    for (int m = 0; m < 5; ++m)
        ap[m] = Ab + (size_t)(wid * 80 + m * 16 + li) * 4096 + kc + lk * 8;

    f32x4  wfetch[8];
    f32x4  acc[5][2] = {};

    // ---- prologue: fetch chunk 0 and stage into buf 0 ----
    #pragma unroll
    for (int rr = 0; rr < 8; ++rr)
        wfetch[rr] = __builtin_nontemporal_load((const f32x4*)(wbase + (size_t)rr * 4096));
    #pragma unroll
    for (int rr = 0; rr < 8; ++rr) {
        const int r = wid * 8 + rr;
        bf16x4 v; v[0] = (__bf16)wfetch[rr][0]; v[1] = (__bf16)wfetch[rr][1];
                  v[2] = (__bf16)wfetch[rr][2]; v[3] = (__bf16)wfetch[rr][3];
        char* d = (char*)&lW[0][0] + r * 512 + (((lane >> 1) ^ (r & 7)) << 4)
                + (lane & 1) * 8;
        *(bf16x4*)d = v;
    }
    __syncthreads();

    for (int c = 0; c < 4; ++c) {
        // issue chunk c+1 fetch (in flight across the whole compute phase)
        if (c < 3) {
            #pragma unroll
            for (int rr = 0; rr < 8; ++rr)
                wfetch[rr] = __builtin_nontemporal_load(
                    (const f32x4*)(wbase + (size_t)rr * 4096 + (c + 1) * 256));
        }

        const char* lwb = (const char*)&lW[c & 1][0];
        #pragma unroll
        for (int s = 0; s < 4; ++s) {
            #pragma unroll
            for (int kk = 0; kk < 2; ++kk) {
                const int kg = c * 256 + s * 64 + kk * 32;
                bf16x8 af[5];
                #pragma unroll
                for (int m = 0; m < 5; ++m)
                    af[m] = *(const bf16x8*)(ap[m] + kg);
                const int slot = s * 8 + kk * 4 + lk;
                bf16x8 wf[2];
                #pragma unroll
                for (int jn = 0; jn < 2; ++jn) {
                    const int j = jn * 16 + li;
                    wf[jn] = *(const bf16x8*)(lwb + j * 512 + ((slot ^ (j & 7)) << 4));
                }
                __builtin_amdgcn_s_setprio(1);
                #pragma unroll
                for (int m = 0; m < 5; ++m) {
                    acc[m][0] = mfma16(af[m], wf[0], acc[m][0]);
                    acc[m][1] = mfma16(af[m], wf[1], acc[m][1]);
                }
                __builtin_amdgcn_s_setprio(0);
            }
        }

        __syncthreads();                  // all reads of current buf done
        if (c < 3) {                      // stage chunk c+1 into other buf
            #pragma unroll
            for (int rr = 0; rr < 8; ++rr) {
                const int r = wid * 8 + rr;
                bf16x4 v; v[0] = (__bf16)wfetch[rr][0]; v[1] = (__bf16)wfetch[rr][1];
                          v[2] = (__bf16)wfetch[rr][2]; v[3] = (__bf16)wfetch[rr][3];
                char* d = (char*)&lW[(c + 1) & 1][0] + r * 512
                        + (((lane >> 1) ^ (r & 7)) << 4) + (lane & 1) * 8;
                *(bf16x4*)d = v;
            }
            __syncthreads();
        }
    }

    // Epilogue: bf16 partials (plain stores; L2 coalesces).
    // C/D layout: col = li, row = lk*4 + r.
    __bf16* Pz = P + (size_t)key * 320 * 4096;
    #pragma unroll
    for (int m = 0; m < 5; ++m) {
        const int row0 = wid * 80 + m * 16 + lk * 4;
        #pragma unroll
        for (int jn = 0; jn < 2; ++jn) {
            const int col = bn + jn * 16 + li;
            #pragma unroll
            for (int r = 0; r < 4; ++r)
                Pz[(size_t)(row0 + r) * 4096 + col] = (__bf16)acc[m][jn][r];
        }
    }
}

// ---------------------------------------------------------------------------
// Stage 2b: reduce 4 bf16 partials -> qT (transposed) and k.
// grid (64 col-tiles, 5 row-tiles, 2 z), 256 threads, 64x64 tiles.
// ---------------------------------------------------------------------------
__global__ __launch_bounds__(256)
void reduce_kernel(const __bf16* __restrict__ P,
                   __bf16* __restrict__ qT, __bf16* __restrict__ kout)
{
    const int z    = blockIdx.z;
    const int col0 = blockIdx.x * 64;
    const int row0 = blockIdx.y * 64;
    const __bf16* P0 = P + ((size_t)z * 4 + 0) * 320 * 4096;
    const __bf16* P1 = P + ((size_t)z * 4 + 1) * 320 * 4096;
    const __bf16* P2 = P + ((size_t)z * 4 + 2) * 320 * 4096;
    const __bf16* P3 = P + ((size_t)z * 4 + 3) * 320 * 4096;

    const int t  = threadIdx.x;
    const int r  = t >> 2;                // 0..63
    const int cc = (t & 3) * 16;          // 0,16,32,48

    float v[16];
    {
        size_t base = (size_t)(row0 + r) * 4096 + col0 + cc;
        #pragma unroll
        for (int i = 0; i < 2; ++i) {
            bf16x8 a = *(const bf16x8*)(P0 + base + i * 8);
            bf16x8 b = *(const bf16x8*)(P1 + base + i * 8);
            bf16x8 c = *(const bf16x8*)(P2 + base + i * 8);
            bf16x8 d = *(const bf16x8*)(P3 + base + i * 8);
            #pragma unroll
            for (int j = 0; j < 8; ++j)
                v[i * 8 + j] = (float)a[j] + (float)b[j] + (float)c[j] + (float)d[j];
        }
    }

    if (z == 1) {  // k: row-major, direct
        __bf16* dst = kout + (size_t)(row0 + r) * 4096 + col0 + cc;
        *(bf16x8*)dst       = pack8f(v);
        *(bf16x8*)(dst + 8) = pack8f(v + 8);
        return;
    }

    // q: transpose via LDS -> qT[b][col][ri]
    __shared__ float lt[64][65];
    #pragma unroll
    for (int i = 0; i < 16; ++i) lt[r][cc + i] = v[i];
    __syncthreads();

    const int col = t & 63;
    const int rr0 = (t >> 6) * 16;
    float w[16];
    #pragma unroll
    for (int i = 0; i < 16; ++i) w[i] = lt[rr0 + i][col];

    const int gr = row0 + rr0;            // multiple of 16; never straddles 160
    const int b  = gr >= 160;
    const int ri = gr - b * 160;
    __bf16* dst = qT + (size_t)b * 4096 * 160 + (size_t)(col0 + col) * 160 + ri;
    *(bf16x8*)dst       = pack8f(w);
    *(bf16x8*)(dst + 8) = pack8f(w + 8);
}

// ---------------------------------------------------------------------------
// Stage 3: kkt (symmetric). One wave per 16x16 output tile, K=1024.
// ---------------------------------------------------------------------------
__global__ __launch_bounds__(64)
void kkt_kernel(const __bf16* __restrict__ kmat, __bf16* __restrict__ kkt)
{
    const int bh = blockIdx.x;            // b*4 + h
    const int b  = bh >> 2, h = bh & 3;
    const int i0 = blockIdx.y * 16;
    const int j0 = blockIdx.z * 16;
    const int lane = threadIdx.x;

    const __bf16* base = kmat + (size_t)b * 160 * 4096 + h * 1024;
    const int ko = (lane >> 4) << 3;
    const __bf16* pa = base + (size_t)(i0 + (lane & 15)) * 4096 + ko;
    const __bf16* pb = base + (size_t)(j0 + (lane & 15)) * 4096 + ko;

    f32x4 acc = {};
    #pragma unroll 4
    for (int kk = 0; kk < 1024; kk += 32) {
        bf16x8 a  = *(const bf16x8*)(pa + kk);
        bf16x8 bb = *(const bf16x8*)(pb + kk);
        acc = mfma16(a, bb, acc);
    }

    #pragma unroll
    for (int r = 0; r < 4; ++r) {
        int i = i0 + ((lane >> 4) << 2) + r;
        int j = j0 + (lane & 15);
        kkt[((size_t)bh * 160 + i) * 160 + j] = (__bf16)(acc[r] * SCALE);
    }
}

// ---------------------------------------------------------------------------
// Stage 4: dots + softplus. Per (b,h): C(4096x160) = qT[b] @ kkt[b,h]^T. K=160.
// ---------------------------------------------------------------------------
__global__ __launch_bounds__(256)
void dots_kernel(const __bf16* __restrict__ qT, const __bf16* __restrict__ kkt,
                 float* __restrict__ out)
{
    const int bh   = blockIdx.z;
    const int b    = bh >> 2;
    const int lane = threadIdx.x & 63;
    const int wid  = threadIdx.x >> 6;
    const int i0   = blockIdx.x * 64 + wid * 16;
    const int j0   = blockIdx.y * 32;

    const __bf16* Ab = qT + (size_t)b * 4096 * 160;
    const __bf16* Bb = kkt + (size_t)bh * 160 * 160;
    const int ko = (lane >> 4) << 3;
    const __bf16* pa  = Ab + (size_t)(i0 + (lane & 15)) * 160 + ko;
    const __bf16* pb0 = Bb + (size_t)(j0 + (lane & 15)) * 160 + ko;
    const __bf16* pb1 = pb0 + 16 * 160;

    f32x4 acc0 = {}, acc1 = {};
    #pragma unroll
    for (int m0 = 0; m0 < 160; m0 += 32) {
        bf16x8 a  = *(const bf16x8*)(pa + m0);
        bf16x8 b0 = *(const bf16x8*)(pb0 + m0);
        bf16x8 b1 = *(const bf16x8*)(pb1 + m0);
        acc0 = mfma16(a, b0, acc0);
        acc1 = mfma16(a, b1, acc1);
    }

    #pragma unroll
    for (int r = 0; r < 4; ++r) {
        int i = i0 + ((lane >> 4) << 2) + r;
        int j = j0 + (lane & 15);
        size_t o = ((size_t)bh * 4096 + i) * 160 + j;
        out[o]      = softplus(acc0[r] * SCALE);
        out[o + 16] = softplus(acc1[r] * SCALE);
    }
}

// ---------------------------------------------------------------------------
extern "C" void kernel_launch(void* const* d_in, const int* in_sizes, int n_in,
                              void* d_out, int out_size, void* d_ws, size_t ws_size,
                              hipStream_t stream)
{
    const float* x  = (const float*)d_in[0];
    const float* y  = (const float*)d_in[1];
    const float* Wq = (const float*)d_in[2];
    const float* Wk = (const float*)d_in[3];
    float* out = (float*)d_out;

    // ws (bf16): qT[2*4096*160], k[320*4096], kkt[8*160*160],
    //            xb[320*4096], yb[320*4096], P[8][320*4096]  (~32 MB)
    __bf16* qT  = (__bf16*)d_ws;
    __bf16* kbf = qT  + (size_t)2 * 4096 * 160;
    __bf16* kkt = kbf + (size_t)320 * 4096;
    __bf16* xb  = kkt + (size_t)8 * 160 * 160;
    __bf16* yb  = xb  + (size_t)320 * 4096;
    __bf16* P   = yb  + (size_t)320 * 4096;

    cvt_kernel   <<<dim3(640, 2),    256, 0, stream>>>(x, y, xb, yb);
    qk_gemm      <<<dim3(1024),      256, 0, stream>>>(yb, xb, Wq, Wk, P);
    reduce_kernel<<<dim3(64, 5, 2),  256, 0, stream>>>(P, qT, kbf);
    kkt_kernel   <<<dim3(8, 10, 10),  64, 0, stream>>>(kbf, kkt);
    dots_kernel  <<<dim3(64, 5, 8),  256, 0, stream>>>(qT, kkt, out);
}

// Round 9
// 151.572 us; speedup vs baseline: 1.0157x; 1.0157x over previous
//
#include <hip/hip_runtime.h>
#include <hip/hip_bf16.h>

// CrossAttention fused pipeline, MI355X (gfx950)
// B=2, N=160, D=4096, H=4, DH=1024, SCALE=1/32 (applied twice)
//
// R8: DRAM-friendly W streaming. Per block, W is fetched in 1 KB-contiguous
// wave-wide f32x4 instructions (copy-kernel pattern -> near-peak DRAM
// efficiency), staged via 2x16 KB LDS chunks ([32 rows][256 f32]), chunk c+1
// reg-prefetched during compute of c. A is read direct-to-register from the
// XCD-pinned L2-resident chunk. 4 blocks/CU. All stores plain (L2 coalesces;
// nt scattered stores were the R7 "rest" regression).
//
// Stage 0: cvt x,y f32 -> bf16
// Stage 1+2: qk GEMM: BM=320, BN=32, Ksplit=4 (Kc=1024). 1024 blocks.
//   key=blockIdx&7=(z<<2)|ks -> XCD pin. bf16 partials P[8][320][4096].
// Stage 2b: reduce 4 partials -> qT[b][d][n] (transposed) and k[320][4096]
// Stage 3: kkt = SCALE * k.k^T per (b,h)      (bf16)
// Stage 4: out = softplus(SCALE * qT @ kkt^T) (f32)

typedef __attribute__((ext_vector_type(4))) float  f32x4;
typedef __attribute__((ext_vector_type(8))) __bf16 bf16x8;
typedef __attribute__((ext_vector_type(4))) __bf16 bf16x4;

#define SCALE 0.03125f

static __device__ __forceinline__ f32x4 mfma16(bf16x8 a, bf16x8 b, f32x4 c) {
    return __builtin_amdgcn_mfma_f32_16x16x32_bf16(a, b, c, 0, 0, 0);
}

static __device__ __forceinline__ bf16x8 pack8(f32x4 a, f32x4 b) {
    bf16x8 r;
    #pragma unroll
    for (int i = 0; i < 4; ++i) { r[i] = (__bf16)a[i]; r[4 + i] = (__bf16)b[i]; }
    return r;
}

static __device__ __forceinline__ bf16x8 pack8f(const float* v) {
    bf16x8 r;
    #pragma unroll
    for (int i = 0; i < 8; ++i) r[i] = (__bf16)v[i];
    return r;
}

static __device__ __forceinline__ float softplus(float x) {
    return fmaxf(x, 0.0f) + log1pf(expf(-fabsf(x)));
}

// ---------------------------------------------------------------------------
// Stage 0: f32 -> bf16 conversion of activations. grid (640, 2), 256 thr.
// ---------------------------------------------------------------------------
__global__ __launch_bounds__(256)
void cvt_kernel(const float* __restrict__ x, const float* __restrict__ y,
                __bf16* __restrict__ xb, __bf16* __restrict__ yb)
{
    const float* src = blockIdx.y ? y : x;
    __bf16* dst = blockIdx.y ? yb : xb;
    size_t i = ((size_t)blockIdx.x * 256 + threadIdx.x) * 8;
    f32x4 a = *(const f32x4*)(src + i);
    f32x4 b = *(const f32x4*)(src + i + 4);
    *(bf16x8*)(dst + i) = pack8(a, b);
}

// ---------------------------------------------------------------------------
// Stage 1+2: C(320x4096) = A(320x4096,bf16) @ W^T, K-split 4, bf16 partials.
// grid 1024 flat: key = blockIdx&7 = (z<<2)|ks [XCD pin], np = blockIdx>>3
// (BN=32 panel). 256 thr = 4 waves, wave tile 80x32 (acc[5][2]).
// Kc=1024 = 4 chunks of 256 f32; chunk fetch = 8 wave-wide f32x4 reads
// (1 KB contiguous per row); double-buffered 16 KB LDS; chunk c+1 is
// reg-prefetched during compute of chunk c (4 inner BK=64 steps).
// A-frags loaded per wave direct from L2 (XCD-resident 640 KB chunk).
// ---------------------------------------------------------------------------
__global__ __launch_bounds__(256, 4)
void qk_gemm(const __bf16* __restrict__ yb, const __bf16* __restrict__ xb,
             const float* __restrict__ Wq, const float* __restrict__ Wk,
             __bf16* __restrict__ P)
{
    const int key = blockIdx.x & 7;
    const int z   = key >> 2;             // 0: q (A=yb,W=Wq)  1: k (A=xb,W=Wk)
    const int ks  = key & 3;
    const int np  = blockIdx.x >> 3;      // 0..127
    const int bn  = np * 32;
    const int kc  = ks * 1024;

    __shared__ __bf16 lW[2][32 * 256];    // 16 KB per buffer

    const int tid  = threadIdx.x;
    const int lane = tid & 63;
    const int wid  = tid >> 6;
    const int li   = lane & 15;
    const int lk   = lane >> 4;

    const __bf16* __restrict__ Ab = z ? xb : yb;   // [320][4096]
    const float*  __restrict__ Wm = z ? Wk : Wq;

    // W fetch: wave wid owns rows wid*8..+7; lane reads f32x4 at col lane*4
    // -> one instruction = 1 KB contiguous of one W row.
    const float* wbase = Wm + (size_t)(bn + wid * 8) * 4096 + kc + lane * 4;

    // A fragment row pointers (per-wave private rows).
    const __bf16* ap[5];
    #pragma unroll
    for (int m = 0; m < 5; ++m)
        ap[m] = Ab + (size_t)(wid * 80 + m * 16 + li) * 4096 + kc + lk * 8;

    f32x4  wfetch[8];
    f32x4  acc[5][2] = {};

    // ---- prologue: fetch chunk 0 and stage into buf 0 ----
    #pragma unroll
    for (int rr = 0; rr < 8; ++rr)
        wfetch[rr] = __builtin_nontemporal_load((const f32x4*)(wbase + (size_t)rr * 4096));
    #pragma unroll
    for (int rr = 0; rr < 8; ++rr) {
        const int r = wid * 8 + rr;
        bf16x4 v; v[0] = (__bf16)wfetch[rr][0]; v[1] = (__bf16)wfetch[rr][1];
                  v[2] = (__bf16)wfetch[rr][2]; v[3] = (__bf16)wfetch[rr][3];
        char* d = (char*)&lW[0][0] + r * 512 + (((lane >> 1) ^ (r & 7)) << 4)
                + (lane & 1) * 8;
        *(bf16x4*)d = v;
    }
    __syncthreads();

    for (int c = 0; c < 4; ++c) {
        // issue chunk c+1 fetch (in flight across the whole compute phase)
        if (c < 3) {
            #pragma unroll
            for (int rr = 0; rr < 8; ++rr)
                wfetch[rr] = __builtin_nontemporal_load(
                    (const f32x4*)(wbase + (size_t)rr * 4096 + (c + 1) * 256));
        }

        const char* lwb = (const char*)&lW[c & 1][0];
        #pragma unroll
        for (int s = 0; s < 4; ++s) {
            #pragma unroll
            for (int kk = 0; kk < 2; ++kk) {
                const int kg = c * 256 + s * 64 + kk * 32;
                bf16x8 af[5];
                #pragma unroll
                for (int m = 0; m < 5; ++m)
                    af[m] = *(const bf16x8*)(ap[m] + kg);
                const int slot = s * 8 + kk * 4 + lk;
                bf16x8 wf[2];
                #pragma unroll
                for (int jn = 0; jn < 2; ++jn) {
                    const int j = jn * 16 + li;
                    wf[jn] = *(const bf16x8*)(lwb + j * 512 + ((slot ^ (j & 7)) << 4));
                }
                __builtin_amdgcn_s_setprio(1);
                #pragma unroll
                for (int m = 0; m < 5; ++m) {
                    acc[m][0] = mfma16(af[m], wf[0], acc[m][0]);
                    acc[m][1] = mfma16(af[m], wf[1], acc[m][1]);
                }
                __builtin_amdgcn_s_setprio(0);
            }
        }

        __syncthreads();                  // all reads of current buf done
        if (c < 3) {                      // stage chunk c+1 into other buf
            #pragma unroll
            for (int rr = 0; rr < 8; ++rr) {
                const int r = wid * 8 + rr;
                bf16x4 v; v[0] = (__bf16)wfetch[rr][0]; v[1] = (__bf16)wfetch[rr][1];
                          v[2] = (__bf16)wfetch[rr][2]; v[3] = (__bf16)wfetch[rr][3];
                char* d = (char*)&lW[(c + 1) & 1][0] + r * 512
                        + (((lane >> 1) ^ (r & 7)) << 4) + (lane & 1) * 8;
                *(bf16x4*)d = v;
            }
            __syncthreads();
        }
    }

    // Epilogue: bf16 partials (plain stores; L2 coalesces).
    // C/D layout: col = li, row = lk*4 + r.
    __bf16* Pz = P + (size_t)key * 320 * 4096;
    #pragma unroll
    for (int m = 0; m < 5; ++m) {
        const int row0 = wid * 80 + m * 16 + lk * 4;
        #pragma unroll
        for (int jn = 0; jn < 2; ++jn) {
            const int col = bn + jn * 16 + li;
            #pragma unroll
            for (int r = 0; r < 4; ++r)
                Pz[(size_t)(row0 + r) * 4096 + col] = (__bf16)acc[m][jn][r];
        }
    }
}

// ---------------------------------------------------------------------------
// Stage 2b: reduce 4 bf16 partials -> qT (transposed) and k.
// grid (64 col-tiles, 5 row-tiles, 2 z), 256 threads, 64x64 tiles.
// ---------------------------------------------------------------------------
__global__ __launch_bounds__(256)
void reduce_kernel(const __bf16* __restrict__ P,
                   __bf16* __restrict__ qT, __bf16* __restrict__ kout)
{
    const int z    = blockIdx.z;
    const int col0 = blockIdx.x * 64;
    const int row0 = blockIdx.y * 64;
    const __bf16* P0 = P + ((size_t)z * 4 + 0) * 320 * 4096;
    const __bf16* P1 = P + ((size_t)z * 4 + 1) * 320 * 4096;
    const __bf16* P2 = P + ((size_t)z * 4 + 2) * 320 * 4096;
    const __bf16* P3 = P + ((size_t)z * 4 + 3) * 320 * 4096;

    const int t  = threadIdx.x;
    const int r  = t >> 2;                // 0..63
    const int cc = (t & 3) * 16;          // 0,16,32,48

    float v[16];
    {
        size_t base = (size_t)(row0 + r) * 4096 + col0 + cc;
        #pragma unroll
        for (int i = 0; i < 2; ++i) {
            bf16x8 a = *(const bf16x8*)(P0 + base + i * 8);
            bf16x8 b = *(const bf16x8*)(P1 + base + i * 8);
            bf16x8 c = *(const bf16x8*)(P2 + base + i * 8);
            bf16x8 d = *(const bf16x8*)(P3 + base + i * 8);
            #pragma unroll
            for (int j = 0; j < 8; ++j)
                v[i * 8 + j] = (float)a[j] + (float)b[j] + (float)c[j] + (float)d[j];
        }
    }

    if (z == 1) {  // k: row-major, direct
        __bf16* dst = kout + (size_t)(row0 + r) * 4096 + col0 + cc;
        *(bf16x8*)dst       = pack8f(v);
        *(bf16x8*)(dst + 8) = pack8f(v + 8);
        return;
    }

    // q: transpose via LDS -> qT[b][col][ri]
    __shared__ float lt[64][65];
    #pragma unroll
    for (int i = 0; i < 16; ++i) lt[r][cc + i] = v[i];
    __syncthreads();

    const int col = t & 63;
    const int rr0 = (t >> 6) * 16;
    float w[16];
    #pragma unroll
    for (int i = 0; i < 16; ++i) w[i] = lt[rr0 + i][col];

    const int gr = row0 + rr0;            // multiple of 16; never straddles 160
    const int b  = gr >= 160;
    const int ri = gr - b * 160;
    __bf16* dst = qT + (size_t)b * 4096 * 160 + (size_t)(col0 + col) * 160 + ri;
    *(bf16x8*)dst       = pack8f(w);
    *(bf16x8*)(dst + 8) = pack8f(w + 8);
}

// ---------------------------------------------------------------------------
// Stage 3: kkt (symmetric). One wave per 16x16 output tile, K=1024.
// ---------------------------------------------------------------------------
__global__ __launch_bounds__(64)
void kkt_kernel(const __bf16* __restrict__ kmat, __bf16* __restrict__ kkt)
{
    const int bh = blockIdx.x;            // b*4 + h
    const int b  = bh >> 2, h = bh & 3;
    const int i0 = blockIdx.y * 16;
    const int j0 = blockIdx.z * 16;
    const int lane = threadIdx.x;

    const __bf16* base = kmat + (size_t)b * 160 * 4096 + h * 1024;
    const int ko = (lane >> 4) << 3;
    const __bf16* pa = base + (size_t)(i0 + (lane & 15)) * 4096 + ko;
    const __bf16* pb = base + (size_t)(j0 + (lane & 15)) * 4096 + ko;

    f32x4 acc = {};
    #pragma unroll 4
    for (int kk = 0; kk < 1024; kk += 32) {
        bf16x8 a  = *(const bf16x8*)(pa + kk);
        bf16x8 bb = *(const bf16x8*)(pb + kk);
        acc = mfma16(a, bb, acc);
    }

    #pragma unroll
    for (int r = 0; r < 4; ++r) {
        int i = i0 + ((lane >> 4) << 2) + r;
        int j = j0 + (lane & 15);
        kkt[((size_t)bh * 160 + i) * 160 + j] = (__bf16)(acc[r] * SCALE);
    }
}

// ---------------------------------------------------------------------------
// Stage 4: dots + softplus. Per (b,h): C(4096x160) = qT[b] @ kkt[b,h]^T. K=160.
// ---------------------------------------------------------------------------
__global__ __launch_bounds__(256)
void dots_kernel(const __bf16* __restrict__ qT, const __bf16* __restrict__ kkt,
                 float* __restrict__ out)
{
    const int bh   = blockIdx.z;
    const int b    = bh >> 2;
    const int lane = threadIdx.x & 63;
    const int wid  = threadIdx.x >> 6;
    const int i0   = blockIdx.x * 64 + wid * 16;
    const int j0   = blockIdx.y * 32;

    const __bf16* Ab = qT + (size_t)b * 4096 * 160;
    const __bf16* Bb = kkt + (size_t)bh * 160 * 160;
    const int ko = (lane >> 4) << 3;
    const __bf16* pa  = Ab + (size_t)(i0 + (lane & 15)) * 160 + ko;
    const __bf16* pb0 = Bb + (size_t)(j0 + (lane & 15)) * 160 + ko;
    const __bf16* pb1 = pb0 + 16 * 160;

    f32x4 acc0 = {}, acc1 = {};
    #pragma unroll
    for (int m0 = 0; m0 < 160; m0 += 32) {
        bf16x8 a  = *(const bf16x8*)(pa + m0);
        bf16x8 b0 = *(const bf16x8*)(pb0 + m0);
        bf16x8 b1 = *(const bf16x8*)(pb1 + m0);
        acc0 = mfma16(a, b0, acc0);
        acc1 = mfma16(a, b1, acc1);
    }

    #pragma unroll
    for (int r = 0; r < 4; ++r) {
        int i = i0 + ((lane >> 4) << 2) + r;
        int j = j0 + (lane & 15);
        size_t o = ((size_t)bh * 4096 + i) * 160 + j;
        out[o]      = softplus(acc0[r] * SCALE);
        out[o + 16] = softplus(acc1[r] * SCALE);
    }
}

// ---------------------------------------------------------------------------
extern "C" void kernel_launch(void* const* d_in, const int* in_sizes, int n_in,
                              void* d_out, int out_size, void* d_ws, size_t ws_size,
                              hipStream_t stream)
{
    const float* x  = (const float*)d_in[0];
    const float* y  = (const float*)d_in[1];
    const float* Wq = (const float*)d_in[2];
    const float* Wk = (const float*)d_in[3];
    float* out = (float*)d_out;

    // ws (bf16): qT[2*4096*160], k[320*4096], kkt[8*160*160],
    //            xb[320*4096], yb[320*4096], P[8][320*4096]  (~32 MB)
    __bf16* qT  = (__bf16*)d_ws;
    __bf16* kbf = qT  + (size_t)2 * 4096 * 160;
    __bf16* kkt = kbf + (size_t)320 * 4096;
    __bf16* xb  = kkt + (size_t)8 * 160 * 160;
    __bf16* yb  = xb  + (size_t)320 * 4096;
    __bf16* P   = yb  + (size_t)320 * 4096;

    cvt_kernel   <<<dim3(640, 2),    256, 0, stream>>>(x, y, xb, yb);
    qk_gemm      <<<dim3(1024),      256, 0, stream>>>(yb, xb, Wq, Wk, P);
    reduce_kernel<<<dim3(64, 5, 2),  256, 0, stream>>>(P, qT, kbf);
    kkt_kernel   <<<dim3(8, 10, 10),  64, 0, stream>>>(kbf, kkt);
    dots_kernel  <<<dim3(64, 5, 8),  256, 0, stream>>>(qT, kkt, out);
}

// Round 11
// 132.540 us; speedup vs baseline: 1.1616x; 1.1436x over previous
//
#include <hip/hip_runtime.h>
#include <hip/hip_bf16.h>

// CrossAttention fused pipeline, MI355X (gfx950)
// B=2, N=160, D=4096, H=4, DH=1024, SCALE=1/32 (applied twice)
//
// R11 = R10 with the staging OOB fixed (8 rows/wave, was 16 -> wrote 64 KB
// past the LDS buffer and read past W's end; core dump).
// W streamed at DRAM-burst granularity with ZERO register cost:
// global_load_lds, one instruction per W row = 1 KB contiguous (m13 copy
// pattern), f32 into LDS (cvt to bf16 at read; VALU is idle). Triple-
// buffered 3x32 KB, counted vmcnt (never drains mid-loop), 2 raw barriers
// per super-step. No K-split -> qk writes qT/k directly, no reduce pass.
// A read direct-to-register from the XCD-pinned L2-resident slab.
//
// Stage 0: cvt x,y f32 -> bf16
// Stage 1+2: qk GEMM: BM=320, BN=32, K=4096 as 16 super-steps of 256.
//   grid 256 = 1 block/CU; z pinned to XCD via blockIdx&7.
// Stage 3: kkt = SCALE * k.k^T per (b,h)      (bf16)
// Stage 4: out = softplus(SCALE * qT @ kkt^T) (f32), j-wide blocks

typedef __attribute__((ext_vector_type(4))) float  f32x4;
typedef __attribute__((ext_vector_type(8))) __bf16 bf16x8;
typedef __attribute__((ext_vector_type(4))) __bf16 bf16x4;

#define SCALE 0.03125f

static __device__ __forceinline__ f32x4 mfma16(bf16x8 a, bf16x8 b, f32x4 c) {
    return __builtin_amdgcn_mfma_f32_16x16x32_bf16(a, b, c, 0, 0, 0);
}

static __device__ __forceinline__ bf16x8 pack8(f32x4 a, f32x4 b) {
    bf16x8 r;
    #pragma unroll
    for (int i = 0; i < 4; ++i) { r[i] = (__bf16)a[i]; r[4 + i] = (__bf16)b[i]; }
    return r;
}

static __device__ __forceinline__ float softplus(float x) {
    return fmaxf(x, 0.0f) + log1pf(expf(-fabsf(x)));
}

static __device__ __forceinline__ void gload_lds16(const void* g, void* l) {
    __builtin_amdgcn_global_load_lds((const __attribute__((address_space(1))) void*)g,
                                     (__attribute__((address_space(3))) void*)l,
                                     16, 0, 0);
}

// ---------------------------------------------------------------------------
// Stage 0: f32 -> bf16 conversion of activations. grid (640, 2), 256 thr.
// ---------------------------------------------------------------------------
__global__ __launch_bounds__(256)
void cvt_kernel(const float* __restrict__ x, const float* __restrict__ y,
                __bf16* __restrict__ xb, __bf16* __restrict__ yb)
{
    const float* src = blockIdx.y ? y : x;
    __bf16* dst = blockIdx.y ? yb : xb;
    size_t i = ((size_t)blockIdx.x * 256 + threadIdx.x) * 8;
    f32x4 a = *(const f32x4*)(src + i);
    f32x4 b = *(const f32x4*)(src + i + 4);
    *(bf16x8*)(dst + i) = pack8(a, b);
}

// ---------------------------------------------------------------------------
// Stage 1+2: C(320x4096) = A(320x4096,bf16) @ W^T. BN=32, full K per block.
// grid 256 flat = 1 block/CU: u=blockIdx&7: z=u>>2, plow=u&3;
// panel = (blockIdx>>3)*4 + plow (0..127); bn = panel*32.
// 256 thr = 4 waves, wave tile 80 rows x 32 cols, acc[5][2] (40 VGPR).
// Per super-step (K=256 f32): W tile 32 rows x 1 KB staged f32 via 8
// global_load_lds per wave (1 KB contiguous each), triple-buffered.
// 16B-piece swizzle: phys piece p holds logical piece p^(row&7), applied
// by pre-swizzling the per-lane GLOBAL source (LDS dest stays linear).
// A-frags: direct global->reg bf16x8 from the L2-resident slab.
// ---------------------------------------------------------------------------
__global__ __launch_bounds__(256, 1)
void qk_gemm(const __bf16* __restrict__ yb, const __bf16* __restrict__ xb,
             const float* __restrict__ Wq, const float* __restrict__ Wk,
             __bf16* __restrict__ qT, __bf16* __restrict__ kout)
{
    const int u     = blockIdx.x & 7;
    const int z     = u >> 2;
    const int panel = ((blockIdx.x >> 3) << 2) + (u & 3);   // 0..127
    const int bn    = panel * 32;

    __shared__ float lW[3 * 32 * 256];    // 3 x 32 KB

    const int tid  = threadIdx.x;
    const int lane = tid & 63;
    const int wid  = tid >> 6;            // 0..3
    const int li   = lane & 15;
    const int lk   = lane >> 4;

    const __bf16* __restrict__ Ab = z ? xb : yb;   // [320][4096]
    const float*  __restrict__ Wm = z ? Wk : Wq;

    // A fragment pointers: row = wid*80 + m*16 + li, k-offset lk*8
    const __bf16* ap[5];
    #pragma unroll
    for (int m = 0; m < 5; ++m)
        ap[m] = Ab + (size_t)(wid * 80 + m * 16 + li) * 4096 + lk * 8;

    f32x4 acc[5][2] = {};

    // ---- W super-step staging: wave wid stages rows wid*8+i, i=0..7 ----
    // One gload_lds = 64 lanes x 16B = 1 KB = one W row's 256 f32.
    // src per lane pre-swizzled: lane l fetches logical piece (l ^ (r&7));
    // r&7 == i&7 since wid*8 is a multiple of 8.
#define ISSUE_SUPER(SUP, BUF)                                                  \
    {                                                                          \
        _Pragma("unroll")                                                      \
        for (int i = 0; i < 8; ++i) {                                          \
            const int r = wid * 8 + i;                                         \
            gload_lds16(Wm + (size_t)(bn + r) * 4096 + (SUP) * 256             \
                           + ((lane ^ (i & 7)) << 2),                          \
                        (char*)lW + (BUF) * 32768 + r * 1024);                 \
        }                                                                      \
    }

    // prologue: issue supers 0 and 1 (8 loads/wave each -> 16 outstanding)
    ISSUE_SUPER(0, 0);
    ISSUE_SUPER(1, 1);

    int cb = 0;                            // compute buffer
    for (int sup = 0; sup < 16; ++sup) {
        if (sup < 14) {
            const int ib = (sup + 2) % 3;
            ISSUE_SUPER(sup + 2, ib);
        }
        // counted wait: retire buf cb's 8 loads; keep up to 2 supers in flight
        if (sup < 14)       asm volatile("s_waitcnt vmcnt(16)" ::: "memory");
        else if (sup == 14) asm volatile("s_waitcnt vmcnt(8)"  ::: "memory");
        else                asm volatile("s_waitcnt vmcnt(0)"  ::: "memory");
        __builtin_amdgcn_s_barrier();
        __builtin_amdgcn_sched_barrier(0);

        const float* LB = lW + cb * 8192;  // f32 units
        #pragma unroll
        for (int sl = 0; sl < 8; ++sl) {
            bf16x8 af[5];
            #pragma unroll
            for (int m = 0; m < 5; ++m)
                af[m] = *(const bf16x8*)(ap[m] + sup * 256 + sl * 32);
            bf16x8 wf[2];
            #pragma unroll
            for (int jn = 0; jn < 2; ++jn) {
                const int j  = jn * 16 + li;
                const int lp = sl * 8 + lk * 2;
                const float* rp = LB + j * 256;
                f32x4 lo = *(const f32x4*)(rp + ((lp ^ (j & 7)) << 2));
                f32x4 hi = *(const f32x4*)(rp + (((lp + 1) ^ (j & 7)) << 2));
                wf[jn] = pack8(lo, hi);
            }
            __builtin_amdgcn_s_setprio(1);
            #pragma unroll
            for (int m = 0; m < 5; ++m) {
                acc[m][0] = mfma16(af[m], wf[0], acc[m][0]);
                acc[m][1] = mfma16(af[m], wf[1], acc[m][1]);
            }
            __builtin_amdgcn_s_setprio(0);
        }

        __builtin_amdgcn_s_barrier();      // protect buf cb from next issue
        __builtin_amdgcn_sched_barrier(0);
        cb = (cb + 1) % 3;
    }
#undef ISSUE_SUPER

    // Epilogue. C/D layout: col = li, row = lk*4 + r.
    if (z == 0) {
        #pragma unroll
        for (int m = 0; m < 5; ++m) {
            const int row0 = wid * 80 + m * 16 + lk * 4;   // 0..316, mult of 4
            const int b  = row0 >= 160;
            const int ri = row0 - b * 160;
            #pragma unroll
            for (int jn = 0; jn < 2; ++jn) {
                const int col = bn + jn * 16 + li;
                bf16x4 v;
                #pragma unroll
                for (int r = 0; r < 4; ++r) v[r] = (__bf16)acc[m][jn][r];
                *(bf16x4*)(qT + (size_t)b * 4096 * 160 + (size_t)col * 160 + ri) = v;
            }
        }
    } else {
        #pragma unroll
        for (int m = 0; m < 5; ++m) {
            const int row0 = wid * 80 + m * 16 + lk * 4;
            #pragma unroll
            for (int jn = 0; jn < 2; ++jn) {
                const int col = bn + jn * 16 + li;
                #pragma unroll
                for (int r = 0; r < 4; ++r)
                    kout[(size_t)(row0 + r) * 4096 + col] = (__bf16)acc[m][jn][r];
            }
        }
    }
}

// ---------------------------------------------------------------------------
// Stage 3: kkt (symmetric). One wave per 16x16 output tile, K=1024.
// ---------------------------------------------------------------------------
__global__ __launch_bounds__(64)
void kkt_kernel(const __bf16* __restrict__ kmat, __bf16* __restrict__ kkt)
{
    const int bh = blockIdx.x;            // b*4 + h
    const int b  = bh >> 2, h = bh & 3;
    const int i0 = blockIdx.y * 16;
    const int j0 = blockIdx.z * 16;
    const int lane = threadIdx.x;

    const __bf16* base = kmat + (size_t)b * 160 * 4096 + h * 1024;
    const int ko = (lane >> 4) << 3;
    const __bf16* pa = base + (size_t)(i0 + (lane & 15)) * 4096 + ko;
    const __bf16* pb = base + (size_t)(j0 + (lane & 15)) * 4096 + ko;

    f32x4 acc = {};
    #pragma unroll 4
    for (int kk = 0; kk < 1024; kk += 32) {
        bf16x8 a  = *(const bf16x8*)(pa + kk);
        bf16x8 bb = *(const bf16x8*)(pb + kk);
        acc = mfma16(a, bb, acc);
    }

    #pragma unroll
    for (int r = 0; r < 4; ++r) {
        int i = i0 + ((lane >> 4) << 2) + r;
        int j = j0 + (lane & 15);
        kkt[((size_t)bh * 160 + i) * 160 + j] = (__bf16)(acc[r] * SCALE);
    }
}

// ---------------------------------------------------------------------------
// Stage 4: dots + softplus. Per (b,h): C(4096x160) = qT[b] @ kkt[b,h]^T.
// K=160, full j-range per block (acc[10]); grid (64 i-tiles, 8 bh).
// ---------------------------------------------------------------------------
__global__ __launch_bounds__(256)
void dots_kernel(const __bf16* __restrict__ qT, const __bf16* __restrict__ kkt,
                 float* __restrict__ out)
{
    const int bh   = blockIdx.y;
    const int b    = bh >> 2;
    const int lane = threadIdx.x & 63;
    const int wid  = threadIdx.x >> 6;
    const int li   = lane & 15;
    const int lk   = lane >> 4;
    const int i0   = blockIdx.x * 64 + wid * 16;

    const __bf16* pa = qT + (size_t)b * 4096 * 160 + (size_t)(i0 + li) * 160 + lk * 8;
    const __bf16* pb = kkt + (size_t)bh * 160 * 160 + (size_t)li * 160 + lk * 8;

    f32x4 acc[10] = {};
    #pragma unroll
    for (int m0 = 0; m0 < 160; m0 += 32) {
        bf16x8 a = *(const bf16x8*)(pa + m0);
        #pragma unroll
        for (int jn = 0; jn < 10; ++jn) {
            bf16x8 bb = *(const bf16x8*)(pb + jn * 16 * 160 + m0);
            acc[jn] = mfma16(a, bb, acc[jn]);
        }
    }

    #pragma unroll
    for (int jn = 0; jn < 10; ++jn) {
        const int j = jn * 16 + li;
        #pragma unroll
        for (int r = 0; r < 4; ++r) {
            const int i = i0 + lk * 4 + r;
            out[((size_t)bh * 4096 + i) * 160 + j] = softplus(acc[jn][r] * SCALE);
        }
    }
}

// ---------------------------------------------------------------------------
extern "C" void kernel_launch(void* const* d_in, const int* in_sizes, int n_in,
                              void* d_out, int out_size, void* d_ws, size_t ws_size,
                              hipStream_t stream)
{
    const float* x  = (const float*)d_in[0];
    const float* y  = (const float*)d_in[1];
    const float* Wq = (const float*)d_in[2];
    const float* Wk = (const float*)d_in[3];
    float* out = (float*)d_out;

    // ws (bf16): qT[2*4096*160], k[320*4096], kkt[8*160*160],
    //            xb[320*4096], yb[320*4096]   (~10.9 MB)
    __bf16* qT  = (__bf16*)d_ws;
    __bf16* kbf = qT  + (size_t)2 * 4096 * 160;
    __bf16* kkt = kbf + (size_t)320 * 4096;
    __bf16* xb  = kkt + (size_t)8 * 160 * 160;
    __bf16* yb  = xb  + (size_t)320 * 4096;

    cvt_kernel <<<dim3(640, 2),    256, 0, stream>>>(x, y, xb, yb);
    qk_gemm    <<<dim3(256),       256, 0, stream>>>(yb, xb, Wq, Wk, qT, kbf);
    kkt_kernel <<<dim3(8, 10, 10),  64, 0, stream>>>(kbf, kkt);
    dots_kernel<<<dim3(64, 8),     256, 0, stream>>>(qT, kkt, out);
}